// Round 1
// baseline (1082.795 us; speedup 1.0000x reference)
//
#include <hip/hip_runtime.h>
#include <math.h>

#define T_DIM 3
#define B_DIM 2048
#define NIMG  (T_DIM * B_DIM)   // 6144

// ===========================================================================
// Activations live in ws as [t][C][H][W][2048] fp32 (innermost = batch b).
// lane = image => coalesced loads on img-minor tensors, wave-uniform weights.
//
// conv0 v2: the NCHW input is image-major, so per-lane taps were 64-line
// gathers. Now each block (t, 64-img group, oh-pair) stages one (ci,ih) input
// row for all 64 images into LDS via coalesced float4 loads (each wave instr
// covers 4 complete image rows), transposed to [img][iw] (stride 68 floats:
// b128-aligned, 2-way bank aliasing = free). Double-buffered => one-row
// prefetch depth hides memory latency behind FMAs.
// ===========================================================================
__global__ __launch_bounds__(256) void conv0_kernel(
    const float* __restrict__ img, const float* __restrict__ w0,
    const float* __restrict__ b0, float* __restrict__ a0)
{
    __shared__ float sb[2][64 * 68];    // 34.8 KB: two (ci,ih) row-sets

    const int bid  = blockIdx.x;
    const int ohp  = bid & 15;          // oh-pair index (oh = 2*ohp + oh_sub)
    const int g    = (bid >> 4) & 31;   // image group of 64
    const int t    = bid >> 9;
    const int tid  = threadIdx.x;
    const int wv   = tid >> 6;          // wave 0..3
    const int lane = tid & 63;
    const int oh_sub = wv >> 1;
    const int half   = wv & 1;
    const int oh   = ohp * 2 + oh_sub;
    const int ow0  = half * 16;
    const int im   = g * 64 + lane;

    // staging decomposition: 16 threads per image row, 4 passes of 16 images
    const int jj16 = tid >> 4;          // 0..15
    const int f4   = tid & 15;          // float4 chunk within 64-float row
    const int ih0  = 4 * ohp - 1;       // first ih of the 6-row window

    float acc[4][16];
#pragma unroll
    for (int j = 0; j < 4; j++) {
        const float bv = b0[t * 4 + j];
#pragma unroll
        for (int k = 0; k < 16; k++) acc[j][k] = bv;
    }
    const float* wt = w0 + t * 192;

    // stage (ci, ih) row-set into dst: dst[j*68 + iw] = row_j[iw]
    auto stage = [&](int ci, int ih, float* dst) {
        if ((unsigned)ih < 64u) {
#pragma unroll
            for (int p = 0; p < 4; ++p) {
                const int j = p * 16 + jj16;
                const float4 v = *(const float4*)(img +
                    ((size_t)((t * 2048 + g * 64 + j) * 3 + ci) << 12) +
                    (ih << 6) + (f4 << 2));
                *(float4*)&dst[j * 68 + (f4 << 2)] = v;
            }
        }
    };

    // consume one staged row: wave uses it iff its kh = r - 2*oh_sub in [0,4)
    auto consume = [&](int ci, int r, int ih, const float* src) {
        const int kh = r - 2 * oh_sub;
        if (kh < 0 || kh > 3 || (unsigned)ih >= 64u) return;
        const float* lrow = src + lane * 68;
        float tap[34];                  // tap[r] = input at iw = 2*ow0-1+r
        if (half == 0) {
            tap[0] = 0.f;               // iw = -1 (padding)
#pragma unroll
            for (int c = 0; c < 8; ++c) {
                const float4 v = *(const float4*)(lrow + 4 * c);
                tap[1 + 4 * c] = v.x; tap[2 + 4 * c] = v.y;
                tap[3 + 4 * c] = v.z; tap[4 + 4 * c] = v.w;
            }
            tap[33] = lrow[32];
        } else {
            tap[0] = lrow[31];
#pragma unroll
            for (int c = 0; c < 8; ++c) {
                const float4 v = *(const float4*)(lrow + 32 + 4 * c);
                tap[1 + 4 * c] = v.x; tap[2 + 4 * c] = v.y;
                tap[3 + 4 * c] = v.z; tap[4 + 4 * c] = v.w;
            }
            tap[33] = 0.f;              // iw = 64 (padding)
        }
        float w_[4][4];
#pragma unroll
        for (int j = 0; j < 4; j++)
#pragma unroll
            for (int kw = 0; kw < 4; kw++)
                w_[j][kw] = wt[((j * 3 + ci) * 4 + kh) * 4 + kw]; // uniform
#pragma unroll
        for (int jj = 0; jj < 16; jj++)
#pragma unroll
            for (int kw = 0; kw < 4; kw++) {
                const float x = tap[2 * jj + kw];
#pragma unroll
                for (int j = 0; j < 4; j++)
                    acc[j][jj] = fmaf(x, w_[j][kw], acc[j][jj]);
            }
    };

    // software pipeline over the 18 (ci, r) stages, double-buffered
    stage(0, ih0, sb[0]);
    __syncthreads();
    int s = 0;
#pragma unroll
    for (int ci = 0; ci < 3; ++ci)
#pragma unroll
        for (int r = 0; r < 6; ++r) {
            if (s < 17) {
                const int rn = (r == 5) ? 0 : r + 1;
                const int cn = (r == 5) ? ci + 1 : ci;
                stage(cn, ih0 + rn, sb[(s + 1) & 1]);
            }
            consume(ci, r, ih0 + r, sb[s & 1]);
            __syncthreads();
            ++s;
        }

    const size_t ob0 = ((size_t)(t * 4096 + oh * 32 + ow0)) * 2048 + im;
#pragma unroll
    for (int j = 0; j < 4; j++)
#pragma unroll
        for (int k = 0; k < 16; k++)
            a0[ob0 + ((size_t)j * 1024 + k) * 2048] = fmaxf(acc[j][k], 0.f);
}

// ---------------------------------------------------------------------------
// Generic mid conv (img-minor in AND out). Wave = (t, img-grp, co-grp, oh),
// full output row in registers. Border taps are compile-time zeros.
// ---------------------------------------------------------------------------
template<int CIN, int COUT, int IH, int OH, int CB>
__device__ __forceinline__ void convmid(
    const float* __restrict__ in, const float* __restrict__ gw,
    const float* __restrict__ gb, float* __restrict__ out,
    int t, int cg, int oh, int im)
{
    const int co0 = cg * CB;
    float acc[CB][OH];
#pragma unroll
    for (int j = 0; j < CB; j++) {
        const float bv = gb[t * COUT + co0 + j];
#pragma unroll
        for (int k = 0; k < OH; k++) acc[j][k] = bv;
    }
    const float* wt = gw + ((size_t)t * COUT + co0) * CIN * 16;
    const size_t inb = ((size_t)t * CIN) * (IH * IH) * 2048 + im;

#pragma unroll 4
    for (int ci = 0; ci < CIN; ci++) {
#pragma unroll
        for (int kh = 0; kh < 4; kh++) {
            const int ih = 2 * oh - 1 + kh;
            if ((unsigned)ih >= (unsigned)IH) continue;  // wave-uniform
            const float* rp = in + inb + (size_t)(ci * IH + ih) * IH * 2048;
            float tap[IH + 2];
            tap[0] = 0.f; tap[IH + 1] = 0.f;
#pragma unroll
            for (int iw = 0; iw < IH; iw++) tap[iw + 1] = rp[(size_t)iw * 2048];
            float w_[CB][4];
#pragma unroll
            for (int j = 0; j < CB; j++)
#pragma unroll
                for (int kw = 0; kw < 4; kw++)
                    w_[j][kw] = wt[((size_t)j * CIN + ci) * 16 + kh * 4 + kw];
#pragma unroll
            for (int ow = 0; ow < OH; ow++)
#pragma unroll
                for (int kw = 0; kw < 4; kw++) {
                    const float x = tap[2 * ow + kw];
#pragma unroll
                    for (int j = 0; j < CB; j++)
                        acc[j][ow] = fmaf(x, w_[j][kw], acc[j][ow]);
                }
        }
    }
    const size_t ob = ((size_t)(t * COUT + co0) * OH * OH + (size_t)oh * OH) * 2048 + im;
#pragma unroll
    for (int j = 0; j < CB; j++)
#pragma unroll
        for (int k = 0; k < OH; k++)
            out[ob + ((size_t)j * OH * OH + k) * 2048] = fmaxf(acc[j][k], 0.f);
}

__global__ __launch_bounds__(256) void conv1_kernel(
    const float* __restrict__ a0, const float* __restrict__ w,
    const float* __restrict__ b, float* __restrict__ a1)
{
    const int wid = blockIdx.x * 4 + (threadIdx.x >> 6);
    const int lane = threadIdx.x & 63;
    const int oh = wid & 15, cg = (wid >> 4) & 1, g = (wid >> 5) & 31, t = wid >> 10;
    convmid<4, 8, 32, 16, 4>(a0, w, b, a1, t, cg, oh, g * 64 + lane);
}

__global__ __launch_bounds__(256) void conv2_kernel(
    const float* __restrict__ a1, const float* __restrict__ w,
    const float* __restrict__ b, float* __restrict__ a2)
{
    const int wid = blockIdx.x * 4 + (threadIdx.x >> 6);
    const int lane = threadIdx.x & 63;
    const int oh = wid & 7, cg = (wid >> 3) & 3, g = (wid >> 5) & 31, t = wid >> 10;
    convmid<8, 16, 16, 8, 4>(a1, w, b, a2, t, cg, oh, g * 64 + lane);
}

__global__ __launch_bounds__(256) void conv3_kernel(
    const float* __restrict__ a2, const float* __restrict__ w,
    const float* __restrict__ b, float* __restrict__ a3)
{
    const int wid = blockIdx.x * 4 + (threadIdx.x >> 6);
    const int lane = threadIdx.x & 63;
    const int oh = wid & 3, cg = (wid >> 2) & 3, g = (wid >> 4) & 31, t = wid >> 9;
    convmid<16, 32, 8, 4, 8>(a2, w, b, a3, t, cg, oh, g * 64 + lane);
}

// ---------------------------------------------------------------------------
// Layer 4: [32][4][4] -> [64][2][2]. CB=4 (16 co-groups) => 384 blocks
// (was 192: <1 wave/SIMD, occupancy-starved).
// ---------------------------------------------------------------------------
__global__ __launch_bounds__(256) void conv4_kernel(
    const float* __restrict__ a3, const float* __restrict__ w4,
    const float* __restrict__ b4, float* __restrict__ a4)
{
    const int wid = blockIdx.x * 4 + (threadIdx.x >> 6);
    const int lane = threadIdx.x & 63;
    const int cg = wid & 15, g = (wid >> 4) & 31, t = wid >> 9;
    const int im = g * 64 + lane;
    const int co0 = cg * 4;

    float acc[4][4];
#pragma unroll
    for (int j = 0; j < 4; j++) {
        const float bv = b4[t * 64 + co0 + j];
#pragma unroll
        for (int p = 0; p < 4; p++) acc[j][p] = bv;
    }
    const float* wt = w4 + ((size_t)t * 64 + co0) * 32 * 16;
    const size_t inb = ((size_t)t * 32) * 16 * 2048 + im;

    for (int ci = 0; ci < 32; ci++) {
        float tin[16];
#pragma unroll
        for (int p = 0; p < 16; p++)
            tin[p] = a3[inb + ((size_t)ci * 16 + p) * 2048];
#pragma unroll
        for (int kh = 0; kh < 4; kh++)
#pragma unroll
            for (int oh = 0; oh < 2; oh++) {
                const int ih = 2 * oh - 1 + kh;
                if (ih < 0 || ih > 3) continue;          // compile-time
#pragma unroll
                for (int ow = 0; ow < 2; ow++)
#pragma unroll
                    for (int kw = 0; kw < 4; kw++) {
                        const int iw = 2 * ow - 1 + kw;
                        if (iw < 0 || iw > 3) continue;  // compile-time
                        const float x = tin[ih * 4 + iw];
#pragma unroll
                        for (int j = 0; j < 4; j++)
                            acc[j][oh * 2 + ow] = fmaf(
                                x, wt[((size_t)j * 32 + ci) * 16 + kh * 4 + kw],
                                acc[j][oh * 2 + ow]);
                    }
            }
    }
#pragma unroll
    for (int j = 0; j < 4; j++)
#pragma unroll
        for (int p = 0; p < 4; p++)
            a4[(((size_t)t * 64 + co0 + j) * 4 + p) * 2048 + im] =
                fmaxf(acc[j][p], 0.f);
}

// ---------------------------------------------------------------------------
// Layer 5: [64][2][2] -> [128]. Only taps (1,1),(1,2),(2,1),(2,2) valid.
// CB=4 (32 co-groups) => 768 blocks (was 384).
// ---------------------------------------------------------------------------
__global__ __launch_bounds__(256) void conv5_kernel(
    const float* __restrict__ a4, const float* __restrict__ w5,
    const float* __restrict__ b5, float* __restrict__ feats)
{
    const int wid = blockIdx.x * 4 + (threadIdx.x >> 6);
    const int lane = threadIdx.x & 63;
    const int cg = wid & 31, g = (wid >> 5) & 31, t = wid >> 10;
    const int im = g * 64 + lane;
    const int co0 = cg * 4;

    float acc[4];
#pragma unroll
    for (int j = 0; j < 4; j++) acc[j] = b5[t * 128 + co0 + j];
    const float* wt = w5 + ((size_t)t * 128 + co0) * 64 * 16;
    const size_t inb = ((size_t)t * 64) * 4 * 2048 + im;

#pragma unroll 4
    for (int ci = 0; ci < 64; ci++) {
        const float x0 = a4[inb + ((size_t)ci * 4 + 0) * 2048];
        const float x1 = a4[inb + ((size_t)ci * 4 + 1) * 2048];
        const float x2 = a4[inb + ((size_t)ci * 4 + 2) * 2048];
        const float x3 = a4[inb + ((size_t)ci * 4 + 3) * 2048];
#pragma unroll
        for (int j = 0; j < 4; j++) {
            const size_t wb = ((size_t)j * 64 + ci) * 16;
            acc[j] = fmaf(x0, wt[wb + 5],  acc[j]);
            acc[j] = fmaf(x1, wt[wb + 6],  acc[j]);
            acc[j] = fmaf(x2, wt[wb + 9],  acc[j]);
            acc[j] = fmaf(x3, wt[wb + 10], acc[j]);
        }
    }
#pragma unroll
    for (int j = 0; j < 4; j++)
        feats[((size_t)t * 128 + co0 + j) * 2048 + im] = fmaxf(acc[j], 0.f);
}

// ===========================================================================
// Tail: replaces the per-batch head_kernel (per-lane weight-row gathers +
// ~10 serial barriers per block) with three img-minor kernels: lane = b,
// activations coalesced, weight loads wave-uniform (scalarized), no LDS,
// no barriers.
// ===========================================================================

// MLP 128->32->32->64 fused with the LSTM input-gemm (w_ih): writes
// xg[t][80][2048] = f @ w_ih^T + b_ih + b_hh. f itself is never stored.
__global__ __launch_bounds__(64) void mlpxg_kernel(
    const float* __restrict__ feats,
    const float* __restrict__ mw1, const float* __restrict__ mb1,
    const float* __restrict__ mw2, const float* __restrict__ mb2,
    const float* __restrict__ mw3, const float* __restrict__ mb3,
    const float* __restrict__ wih, const float* __restrict__ bih,
    const float* __restrict__ bhh, float* __restrict__ xg)
{
    const int tb = blockIdx.x;           // 0..95
    const int t  = tb >> 5, bg = tb & 31;
    const int b  = bg * 64 + threadIdx.x;

    float x[128];
#pragma unroll
    for (int d = 0; d < 128; ++d)
        x[d] = feats[((size_t)t * 128 + d) * 2048 + b];

    float h1[32];
#pragma unroll
    for (int o = 0; o < 32; ++o) {
        float a = mb1[o];
        const float4* wr = (const float4*)(mw1 + o * 128);   // uniform
#pragma unroll
        for (int q = 0; q < 32; ++q) {
            const float4 w = wr[q];
            a = fmaf(w.x, x[4 * q + 0], a); a = fmaf(w.y, x[4 * q + 1], a);
            a = fmaf(w.z, x[4 * q + 2], a); a = fmaf(w.w, x[4 * q + 3], a);
        }
        h1[o] = fmaxf(a, 0.f);
    }
    float h2[32];
#pragma unroll
    for (int o = 0; o < 32; ++o) {
        float a = mb2[o];
        const float4* wr = (const float4*)(mw2 + o * 32);
#pragma unroll
        for (int q = 0; q < 8; ++q) {
            const float4 w = wr[q];
            a = fmaf(w.x, h1[4 * q + 0], a); a = fmaf(w.y, h1[4 * q + 1], a);
            a = fmaf(w.z, h1[4 * q + 2], a); a = fmaf(w.w, h1[4 * q + 3], a);
        }
        h2[o] = fmaxf(a, 0.f);
    }
    float f_[64];
#pragma unroll
    for (int o = 0; o < 64; ++o) {
        float a = mb3[o];
        const float4* wr = (const float4*)(mw3 + o * 32);
#pragma unroll
        for (int q = 0; q < 8; ++q) {
            const float4 w = wr[q];
            a = fmaf(w.x, h2[4 * q + 0], a); a = fmaf(w.y, h2[4 * q + 1], a);
            a = fmaf(w.z, h2[4 * q + 2], a); a = fmaf(w.w, h2[4 * q + 3], a);
        }
        f_[o] = a;                        // no relu (reference)
    }
#pragma unroll
    for (int i = 0; i < 80; ++i) {
        float a = bih[i] + bhh[i];
        const float4* wr = (const float4*)(wih + i * 64);
#pragma unroll
        for (int q = 0; q < 16; ++q) {
            const float4 w = wr[q];
            a = fmaf(w.x, f_[4 * q + 0], a); a = fmaf(w.y, f_[4 * q + 1], a);
            a = fmaf(w.z, f_[4 * q + 2], a); a = fmaf(w.w, f_[4 * q + 3], a);
        }
        xg[((size_t)t * 80 + i) * 2048 + b] = a;
    }
}

// LSTM recurrence only (x-gemm precomputed into xg). h,c in registers.
__global__ __launch_bounds__(64) void lstm_kernel(
    const float* __restrict__ xg, const float* __restrict__ whh,
    float* __restrict__ hseq)
{
    const int b = blockIdx.x * 64 + threadIdx.x;
    float h[20], c[20];
#pragma unroll
    for (int j = 0; j < 20; ++j) { h[j] = 0.f; c[j] = 0.f; }

    for (int t = 0; t < 3; ++t) {
        float gv[80];
#pragma unroll
        for (int i = 0; i < 80; ++i) {
            float a = xg[((size_t)t * 80 + i) * 2048 + b];
            const float4* wr = (const float4*)(whh + i * 20);  // uniform
#pragma unroll
            for (int q = 0; q < 5; ++q) {
                const float4 w = wr[q];
                a = fmaf(w.x, h[4 * q + 0], a); a = fmaf(w.y, h[4 * q + 1], a);
                a = fmaf(w.z, h[4 * q + 2], a); a = fmaf(w.w, h[4 * q + 3], a);
            }
            gv[i] = a;
        }
#pragma unroll
        for (int j = 0; j < 20; ++j) {                       // torch order i,f,g,o
            const float ig = 1.f / (1.f + expf(-gv[j]));
            const float fg = 1.f / (1.f + expf(-gv[20 + j]));
            const float gt = tanhf(gv[40 + j]);
            const float og = 1.f / (1.f + expf(-gv[60 + j]));
            const float cn = fg * c[j] + ig * gt;
            c[j] = cn;
            const float hn = og * tanhf(cn);
            h[j] = hn;
            hseq[((size_t)t * 20 + j) * 2048 + b] = hn;
        }
    }
}

// 20 heads 20->32->32->1, grid (96 tb-groups, 20 heads), lane = b.
__global__ __launch_bounds__(64) void heads_kernel(
    const float* __restrict__ hseq,
    const float* __restrict__ hw1, const float* __restrict__ hb1,
    const float* __restrict__ hw2, const float* __restrict__ hb2,
    const float* __restrict__ hw3, const float* __restrict__ hb3,
    float* __restrict__ out)
{
    const int t  = blockIdx.x >> 5, bg = blockIdx.x & 31;
    const int k  = blockIdx.y;
    const int b  = bg * 64 + threadIdx.x;

    float xv[20];
#pragma unroll
    for (int d = 0; d < 20; ++d)
        xv[d] = hseq[((size_t)t * 20 + d) * 2048 + b];

    float a1[32];
#pragma unroll
    for (int o = 0; o < 32; ++o) {
        float a = hb1[k * 32 + o];
        const float4* wr = (const float4*)(hw1 + ((size_t)k * 32 + o) * 20);
#pragma unroll
        for (int q = 0; q < 5; ++q) {
            const float4 w = wr[q];
            a = fmaf(w.x, xv[4 * q + 0], a); a = fmaf(w.y, xv[4 * q + 1], a);
            a = fmaf(w.z, xv[4 * q + 2], a); a = fmaf(w.w, xv[4 * q + 3], a);
        }
        a1[o] = fmaxf(a, 0.f);
    }
    float a2[32];
#pragma unroll
    for (int o = 0; o < 32; ++o) {
        float a = hb2[k * 32 + o];
        const float4* wr = (const float4*)(hw2 + ((size_t)k * 32 + o) * 32);
#pragma unroll
        for (int q = 0; q < 8; ++q) {
            const float4 w = wr[q];
            a = fmaf(w.x, a1[4 * q + 0], a); a = fmaf(w.y, a1[4 * q + 1], a);
            a = fmaf(w.z, a1[4 * q + 2], a); a = fmaf(w.w, a1[4 * q + 3], a);
        }
        a2[o] = fmaxf(a, 0.f);
    }
    float r = hb3[k];
    const float4* wr = (const float4*)(hw3 + (size_t)k * 32);
#pragma unroll
    for (int q = 0; q < 8; ++q) {
        const float4 w = wr[q];
        r = fmaf(w.x, a2[4 * q + 0], r); r = fmaf(w.y, a2[4 * q + 1], r);
        r = fmaf(w.z, a2[4 * q + 2], r); r = fmaf(w.w, a2[4 * q + 3], r);
    }
    out[((size_t)k * 3 + t) * 2048 + b] = r;
}

// ---------------------------------------------------------------------------
extern "C" void kernel_launch(void* const* d_in, const int* in_sizes, int n_in,
                              void* d_out, int out_size, void* d_ws, size_t ws_size,
                              hipStream_t stream)
{
    const float* img = (const float*)d_in[0];
    const float* ew0 = (const float*)d_in[1];  const float* eb0 = (const float*)d_in[2];
    const float* ew1 = (const float*)d_in[3];  const float* eb1 = (const float*)d_in[4];
    const float* ew2 = (const float*)d_in[5];  const float* eb2 = (const float*)d_in[6];
    const float* ew3 = (const float*)d_in[7];  const float* eb3 = (const float*)d_in[8];
    const float* ew4 = (const float*)d_in[9];  const float* eb4 = (const float*)d_in[10];
    const float* ew5 = (const float*)d_in[11]; const float* eb5 = (const float*)d_in[12];
    const float* mw1 = (const float*)d_in[13]; const float* mb1 = (const float*)d_in[14];
    const float* mw2 = (const float*)d_in[15]; const float* mb2 = (const float*)d_in[16];
    const float* mw3 = (const float*)d_in[17]; const float* mb3 = (const float*)d_in[18];
    const float* wih = (const float*)d_in[19]; const float* whh = (const float*)d_in[20];
    const float* bih = (const float*)d_in[21]; const float* bhh = (const float*)d_in[22];
    const float* hw1 = (const float*)d_in[23]; const float* hb1 = (const float*)d_in[24];
    const float* hw2 = (const float*)d_in[25]; const float* hb2 = (const float*)d_in[26];
    const float* hw3 = (const float*)d_in[27]; const float* hb3 = (const float*)d_in[28];

    // ws layout (floats), with buffer reuse:
    //   A: 25,165,824 f (a0 [3][4][32][32][2048]; later a2, then a4)
    //   B: 12,582,912 f (a1 [3][8][16][16][2048]; later a3; then xg+hseq)
    //   C:    786,432 f (feats [3][128][2048])
    float* A  = (float*)d_ws;
    float* B  = A + 25165824;
    float* C  = B + 12582912;
    float* XG = B;               // a3 dead after conv4: xg [3][80][2048]
    float* HS = B + 491520;      // hseq [3][20][2048]

    conv0_kernel<<<1536, 256, 0, stream>>>(img, ew0, eb0, A);
    conv1_kernel<<< 768, 256, 0, stream>>>(A, ew1, eb1, B);
    conv2_kernel<<< 768, 256, 0, stream>>>(B, ew2, eb2, A);
    conv3_kernel<<< 384, 256, 0, stream>>>(A, ew3, eb3, B);
    conv4_kernel<<< 384, 256, 0, stream>>>(B, ew4, eb4, A);
    conv5_kernel<<< 768, 256, 0, stream>>>(A, ew5, eb5, C);
    mlpxg_kernel<<<96, 64, 0, stream>>>(C, mw1, mb1, mw2, mb2, mw3, mb3,
                                        wih, bih, bhh, XG);
    lstm_kernel<<<32, 64, 0, stream>>>(XG, whh, HS);
    heads_kernel<<<dim3(96, 20), 64, 0, stream>>>(HS, hw1, hb1, hw2, hb2,
                                                  hw3, hb3, (float*)d_out);
}

// Round 2
// 1078.812 us; speedup vs baseline: 1.0037x; 1.0037x over previous
//
#include <hip/hip_runtime.h>
#include <math.h>

#define T_DIM 3
#define B_DIM 2048
#define NIMG  (T_DIM * B_DIM)   // 6144

// ===========================================================================
// Activations live in ws as [t][C][H][W][2048] fp32 (innermost = batch b).
// lane = image => coalesced loads on img-minor tensors, wave-uniform weights.
//
// conv0 v2: the NCHW input is image-major, so per-lane taps were 64-line
// gathers. Now each block (t, 64-img group, oh-pair) stages one (ci,ih) input
// row for all 64 images into LDS via coalesced float4 loads (each wave instr
// covers 4 complete image rows), transposed to [img][iw] (stride 68 floats:
// b128-aligned, 2-way bank aliasing = free). Double-buffered => one-row
// prefetch depth hides memory latency behind FMAs.
// ===========================================================================
__global__ __launch_bounds__(256) void conv0_kernel(
    const float* __restrict__ img, const float* __restrict__ w0,
    const float* __restrict__ b0, float* __restrict__ a0)
{
    __shared__ float sb[2][64 * 68];    // 34.8 KB: two (ci,ih) row-sets

    const int bid  = blockIdx.x;
    const int ohp  = bid & 15;          // oh-pair index (oh = 2*ohp + oh_sub)
    const int g    = (bid >> 4) & 31;   // image group of 64
    const int t    = bid >> 9;
    const int tid  = threadIdx.x;
    const int wv   = tid >> 6;          // wave 0..3
    const int lane = tid & 63;
    const int oh_sub = wv >> 1;
    const int half   = wv & 1;
    const int oh   = ohp * 2 + oh_sub;
    const int ow0  = half * 16;
    const int im   = g * 64 + lane;

    // staging decomposition: 16 threads per image row, 4 passes of 16 images
    const int jj16 = tid >> 4;          // 0..15
    const int f4   = tid & 15;          // float4 chunk within 64-float row
    const int ih0  = 4 * ohp - 1;       // first ih of the 6-row window

    float acc[4][16];
#pragma unroll
    for (int j = 0; j < 4; j++) {
        const float bv = b0[t * 4 + j];
#pragma unroll
        for (int k = 0; k < 16; k++) acc[j][k] = bv;
    }
    const float* wt = w0 + t * 192;

    // stage (ci, ih) row-set into dst: dst[j*68 + iw] = row_j[iw]
    auto stage = [&](int ci, int ih, float* dst) {
        if ((unsigned)ih < 64u) {
#pragma unroll
            for (int p = 0; p < 4; ++p) {
                const int j = p * 16 + jj16;
                const float4 v = *(const float4*)(img +
                    ((size_t)((t * 2048 + g * 64 + j) * 3 + ci) << 12) +
                    (ih << 6) + (f4 << 2));
                *(float4*)&dst[j * 68 + (f4 << 2)] = v;
            }
        }
    };

    // consume one staged row: wave uses it iff its kh = r - 2*oh_sub in [0,4)
    auto consume = [&](int ci, int r, int ih, const float* src) {
        const int kh = r - 2 * oh_sub;
        if (kh < 0 || kh > 3 || (unsigned)ih >= 64u) return;
        const float* lrow = src + lane * 68;
        float tap[34];                  // tap[r] = input at iw = 2*ow0-1+r
        if (half == 0) {
            tap[0] = 0.f;               // iw = -1 (padding)
#pragma unroll
            for (int c = 0; c < 8; ++c) {
                const float4 v = *(const float4*)(lrow + 4 * c);
                tap[1 + 4 * c] = v.x; tap[2 + 4 * c] = v.y;
                tap[3 + 4 * c] = v.z; tap[4 + 4 * c] = v.w;
            }
            tap[33] = lrow[32];
        } else {
            tap[0] = lrow[31];
#pragma unroll
            for (int c = 0; c < 8; ++c) {
                const float4 v = *(const float4*)(lrow + 32 + 4 * c);
                tap[1 + 4 * c] = v.x; tap[2 + 4 * c] = v.y;
                tap[3 + 4 * c] = v.z; tap[4 + 4 * c] = v.w;
            }
            tap[33] = 0.f;              // iw = 64 (padding)
        }
        float w_[4][4];
#pragma unroll
        for (int j = 0; j < 4; j++)
#pragma unroll
            for (int kw = 0; kw < 4; kw++)
                w_[j][kw] = wt[((j * 3 + ci) * 4 + kh) * 4 + kw]; // uniform
#pragma unroll
        for (int jj = 0; jj < 16; jj++)
#pragma unroll
            for (int kw = 0; kw < 4; kw++) {
                const float x = tap[2 * jj + kw];
#pragma unroll
                for (int j = 0; j < 4; j++)
                    acc[j][jj] = fmaf(x, w_[j][kw], acc[j][jj]);
            }
    };

    // software pipeline over the 18 (ci, r) stages, double-buffered
    stage(0, ih0, sb[0]);
    __syncthreads();
    int s = 0;
#pragma unroll
    for (int ci = 0; ci < 3; ++ci)
#pragma unroll
        for (int r = 0; r < 6; ++r) {
            if (s < 17) {
                const int rn = (r == 5) ? 0 : r + 1;
                const int cn = (r == 5) ? ci + 1 : ci;
                stage(cn, ih0 + rn, sb[(s + 1) & 1]);
            }
            consume(ci, r, ih0 + r, sb[s & 1]);
            __syncthreads();
            ++s;
        }

    const size_t ob0 = ((size_t)(t * 4096 + oh * 32 + ow0)) * 2048 + im;
#pragma unroll
    for (int j = 0; j < 4; j++)
#pragma unroll
        for (int k = 0; k < 16; k++)
            a0[ob0 + ((size_t)j * 1024 + k) * 2048] = fmaxf(acc[j][k], 0.f);
}

// ---------------------------------------------------------------------------
// Generic mid conv (img-minor in AND out). Wave = (t, img-grp, co-grp, oh),
// full output row in registers. Border taps are compile-time zeros.
// ---------------------------------------------------------------------------
template<int CIN, int COUT, int IH, int OH, int CB>
__device__ __forceinline__ void convmid(
    const float* __restrict__ in, const float* __restrict__ gw,
    const float* __restrict__ gb, float* __restrict__ out,
    int t, int cg, int oh, int im)
{
    const int co0 = cg * CB;
    float acc[CB][OH];
#pragma unroll
    for (int j = 0; j < CB; j++) {
        const float bv = gb[t * COUT + co0 + j];
#pragma unroll
        for (int k = 0; k < OH; k++) acc[j][k] = bv;
    }
    const float* wt = gw + ((size_t)t * COUT + co0) * CIN * 16;
    const size_t inb = ((size_t)t * CIN) * (IH * IH) * 2048 + im;

#pragma unroll 4
    for (int ci = 0; ci < CIN; ci++) {
#pragma unroll
        for (int kh = 0; kh < 4; kh++) {
            const int ih = 2 * oh - 1 + kh;
            if ((unsigned)ih >= (unsigned)IH) continue;  // wave-uniform
            const float* rp = in + inb + (size_t)(ci * IH + ih) * IH * 2048;
            float tap[IH + 2];
            tap[0] = 0.f; tap[IH + 1] = 0.f;
#pragma unroll
            for (int iw = 0; iw < IH; iw++) tap[iw + 1] = rp[(size_t)iw * 2048];
            float w_[CB][4];
#pragma unroll
            for (int j = 0; j < CB; j++)
#pragma unroll
                for (int kw = 0; kw < 4; kw++)
                    w_[j][kw] = wt[((size_t)j * CIN + ci) * 16 + kh * 4 + kw];
#pragma unroll
            for (int ow = 0; ow < OH; ow++)
#pragma unroll
                for (int kw = 0; kw < 4; kw++) {
                    const float x = tap[2 * ow + kw];
#pragma unroll
                    for (int j = 0; j < CB; j++)
                        acc[j][ow] = fmaf(x, w_[j][kw], acc[j][ow]);
                }
        }
    }
    const size_t ob = ((size_t)(t * COUT + co0) * OH * OH + (size_t)oh * OH) * 2048 + im;
#pragma unroll
    for (int j = 0; j < CB; j++)
#pragma unroll
        for (int k = 0; k < OH; k++)
            out[ob + ((size_t)j * OH * OH + k) * 2048] = fmaxf(acc[j][k], 0.f);
}

__global__ __launch_bounds__(256) void conv1_kernel(
    const float* __restrict__ a0, const float* __restrict__ w,
    const float* __restrict__ b, float* __restrict__ a1)
{
    const int wid = blockIdx.x * 4 + (threadIdx.x >> 6);
    const int lane = threadIdx.x & 63;
    const int oh = wid & 15, cg = (wid >> 4) & 1, g = (wid >> 5) & 31, t = wid >> 10;
    convmid<4, 8, 32, 16, 4>(a0, w, b, a1, t, cg, oh, g * 64 + lane);
}

__global__ __launch_bounds__(256) void conv2_kernel(
    const float* __restrict__ a1, const float* __restrict__ w,
    const float* __restrict__ b, float* __restrict__ a2)
{
    const int wid = blockIdx.x * 4 + (threadIdx.x >> 6);
    const int lane = threadIdx.x & 63;
    const int oh = wid & 7, cg = (wid >> 3) & 3, g = (wid >> 5) & 31, t = wid >> 10;
    convmid<8, 16, 16, 8, 4>(a1, w, b, a2, t, cg, oh, g * 64 + lane);
}

__global__ __launch_bounds__(256) void conv3_kernel(
    const float* __restrict__ a2, const float* __restrict__ w,
    const float* __restrict__ b, float* __restrict__ a3)
{
    const int wid = blockIdx.x * 4 + (threadIdx.x >> 6);
    const int lane = threadIdx.x & 63;
    const int oh = wid & 3, cg = (wid >> 2) & 3, g = (wid >> 4) & 31, t = wid >> 9;
    convmid<16, 32, 8, 4, 8>(a2, w, b, a3, t, cg, oh, g * 64 + lane);
}

// ---------------------------------------------------------------------------
// Layer 4: [32][4][4] -> [64][2][2]. CB=4 (16 co-groups) => 384 blocks.
// ---------------------------------------------------------------------------
__global__ __launch_bounds__(256) void conv4_kernel(
    const float* __restrict__ a3, const float* __restrict__ w4,
    const float* __restrict__ b4, float* __restrict__ a4)
{
    const int wid = blockIdx.x * 4 + (threadIdx.x >> 6);
    const int lane = threadIdx.x & 63;
    const int cg = wid & 15, g = (wid >> 4) & 31, t = wid >> 9;
    const int im = g * 64 + lane;
    const int co0 = cg * 4;

    float acc[4][4];
#pragma unroll
    for (int j = 0; j < 4; j++) {
        const float bv = b4[t * 64 + co0 + j];
#pragma unroll
        for (int p = 0; p < 4; p++) acc[j][p] = bv;
    }
    const float* wt = w4 + ((size_t)t * 64 + co0) * 32 * 16;
    const size_t inb = ((size_t)t * 32) * 16 * 2048 + im;

    for (int ci = 0; ci < 32; ci++) {
        float tin[16];
#pragma unroll
        for (int p = 0; p < 16; p++)
            tin[p] = a3[inb + ((size_t)ci * 16 + p) * 2048];
#pragma unroll
        for (int kh = 0; kh < 4; kh++)
#pragma unroll
            for (int oh = 0; oh < 2; oh++) {
                const int ih = 2 * oh - 1 + kh;
                if (ih < 0 || ih > 3) continue;          // compile-time
#pragma unroll
                for (int ow = 0; ow < 2; ow++)
#pragma unroll
                    for (int kw = 0; kw < 4; kw++) {
                        const int iw = 2 * ow - 1 + kw;
                        if (iw < 0 || iw > 3) continue;  // compile-time
                        const float x = tin[ih * 4 + iw];
#pragma unroll
                        for (int j = 0; j < 4; j++)
                            acc[j][oh * 2 + ow] = fmaf(
                                x, wt[((size_t)j * 32 + ci) * 16 + kh * 4 + kw],
                                acc[j][oh * 2 + ow]);
                    }
            }
    }
#pragma unroll
    for (int j = 0; j < 4; j++)
#pragma unroll
        for (int p = 0; p < 4; p++)
            a4[(((size_t)t * 64 + co0 + j) * 4 + p) * 2048 + im] =
                fmaxf(acc[j][p], 0.f);
}

// ---------------------------------------------------------------------------
// Layer 5: [64][2][2] -> [128]. Only taps (1,1),(1,2),(2,1),(2,2) valid.
// ---------------------------------------------------------------------------
__global__ __launch_bounds__(256) void conv5_kernel(
    const float* __restrict__ a4, const float* __restrict__ w5,
    const float* __restrict__ b5, float* __restrict__ feats)
{
    const int wid = blockIdx.x * 4 + (threadIdx.x >> 6);
    const int lane = threadIdx.x & 63;
    const int cg = wid & 31, g = (wid >> 5) & 31, t = wid >> 10;
    const int im = g * 64 + lane;
    const int co0 = cg * 4;

    float acc[4];
#pragma unroll
    for (int j = 0; j < 4; j++) acc[j] = b5[t * 128 + co0 + j];
    const float* wt = w5 + ((size_t)t * 128 + co0) * 64 * 16;
    const size_t inb = ((size_t)t * 64) * 4 * 2048 + im;

#pragma unroll 4
    for (int ci = 0; ci < 64; ci++) {
        const float x0 = a4[inb + ((size_t)ci * 4 + 0) * 2048];
        const float x1 = a4[inb + ((size_t)ci * 4 + 1) * 2048];
        const float x2 = a4[inb + ((size_t)ci * 4 + 2) * 2048];
        const float x3 = a4[inb + ((size_t)ci * 4 + 3) * 2048];
#pragma unroll
        for (int j = 0; j < 4; j++) {
            const size_t wb = ((size_t)j * 64 + ci) * 16;
            acc[j] = fmaf(x0, wt[wb + 5],  acc[j]);
            acc[j] = fmaf(x1, wt[wb + 6],  acc[j]);
            acc[j] = fmaf(x2, wt[wb + 9],  acc[j]);
            acc[j] = fmaf(x3, wt[wb + 10], acc[j]);
        }
    }
#pragma unroll
    for (int j = 0; j < 4; j++)
        feats[((size_t)t * 128 + co0 + j) * 2048 + im] = fmaxf(acc[j], 0.f);
}

// ===========================================================================
// Tail (img-minor, lane = b, wave-uniform weights, no LDS, no barriers).
// __launch_bounds__(64, 1): min 1 wave/EU => allocator may use up to 512
// VGPRs. Round 1 used plain (64) and the allocator picked 84 VGPRs,
// spilling ~180 floats/thread to scratch => 193 us at 0.8% VALUBusy.
// These kernels hold 100-260 live floats; they MUST be register-resident.
// ===========================================================================

// MLP 128->32->32->64 fused with the LSTM input-gemm (w_ih): writes
// xg[t][80][2048] = f @ w_ih^T + b_ih + b_hh. f itself is never stored.
__global__ __launch_bounds__(64, 1) void mlpxg_kernel(
    const float* __restrict__ feats,
    const float* __restrict__ mw1, const float* __restrict__ mb1,
    const float* __restrict__ mw2, const float* __restrict__ mb2,
    const float* __restrict__ mw3, const float* __restrict__ mb3,
    const float* __restrict__ wih, const float* __restrict__ bih,
    const float* __restrict__ bhh, float* __restrict__ xg)
{
    const int tb = blockIdx.x;           // 0..95
    const int t  = tb >> 5, bg = tb & 31;
    const int b  = bg * 64 + threadIdx.x;

    float x[128];
#pragma unroll
    for (int d = 0; d < 128; ++d)
        x[d] = feats[((size_t)t * 128 + d) * 2048 + b];

    float h1[32];
#pragma unroll
    for (int o = 0; o < 32; ++o) {
        float a = mb1[o];
        const float4* wr = (const float4*)(mw1 + o * 128);   // uniform
#pragma unroll
        for (int q = 0; q < 32; ++q) {
            const float4 w = wr[q];
            a = fmaf(w.x, x[4 * q + 0], a); a = fmaf(w.y, x[4 * q + 1], a);
            a = fmaf(w.z, x[4 * q + 2], a); a = fmaf(w.w, x[4 * q + 3], a);
        }
        h1[o] = fmaxf(a, 0.f);
    }
    float h2[32];
#pragma unroll
    for (int o = 0; o < 32; ++o) {
        float a = mb2[o];
        const float4* wr = (const float4*)(mw2 + o * 32);
#pragma unroll
        for (int q = 0; q < 8; ++q) {
            const float4 w = wr[q];
            a = fmaf(w.x, h1[4 * q + 0], a); a = fmaf(w.y, h1[4 * q + 1], a);
            a = fmaf(w.z, h1[4 * q + 2], a); a = fmaf(w.w, h1[4 * q + 3], a);
        }
        h2[o] = fmaxf(a, 0.f);
    }
    float f_[64];
#pragma unroll
    for (int o = 0; o < 64; ++o) {
        float a = mb3[o];
        const float4* wr = (const float4*)(mw3 + o * 32);
#pragma unroll
        for (int q = 0; q < 8; ++q) {
            const float4 w = wr[q];
            a = fmaf(w.x, h2[4 * q + 0], a); a = fmaf(w.y, h2[4 * q + 1], a);
            a = fmaf(w.z, h2[4 * q + 2], a); a = fmaf(w.w, h2[4 * q + 3], a);
        }
        f_[o] = a;                        // no relu (reference)
    }
#pragma unroll
    for (int i = 0; i < 80; ++i) {
        float a = bih[i] + bhh[i];
        const float4* wr = (const float4*)(wih + i * 64);
#pragma unroll
        for (int q = 0; q < 16; ++q) {
            const float4 w = wr[q];
            a = fmaf(w.x, f_[4 * q + 0], a); a = fmaf(w.y, f_[4 * q + 1], a);
            a = fmaf(w.z, f_[4 * q + 2], a); a = fmaf(w.w, f_[4 * q + 3], a);
        }
        xg[((size_t)t * 80 + i) * 2048 + b] = a;
    }
}

// LSTM recurrence only (x-gemm precomputed into xg). h,c in registers.
__global__ __launch_bounds__(64, 1) void lstm_kernel(
    const float* __restrict__ xg, const float* __restrict__ whh,
    float* __restrict__ hseq)
{
    const int b = blockIdx.x * 64 + threadIdx.x;
    float h[20], c[20];
#pragma unroll
    for (int j = 0; j < 20; ++j) { h[j] = 0.f; c[j] = 0.f; }

    for (int t = 0; t < 3; ++t) {
        float gv[80];
#pragma unroll
        for (int i = 0; i < 80; ++i) {
            float a = xg[((size_t)t * 80 + i) * 2048 + b];
            const float4* wr = (const float4*)(whh + i * 20);  // uniform
#pragma unroll
            for (int q = 0; q < 5; ++q) {
                const float4 w = wr[q];
                a = fmaf(w.x, h[4 * q + 0], a); a = fmaf(w.y, h[4 * q + 1], a);
                a = fmaf(w.z, h[4 * q + 2], a); a = fmaf(w.w, h[4 * q + 3], a);
            }
            gv[i] = a;
        }
#pragma unroll
        for (int j = 0; j < 20; ++j) {                       // torch order i,f,g,o
            const float ig = 1.f / (1.f + expf(-gv[j]));
            const float fg = 1.f / (1.f + expf(-gv[20 + j]));
            const float gt = tanhf(gv[40 + j]);
            const float og = 1.f / (1.f + expf(-gv[60 + j]));
            const float cn = fg * c[j] + ig * gt;
            c[j] = cn;
            const float hn = og * tanhf(cn);
            h[j] = hn;
            hseq[((size_t)t * 20 + j) * 2048 + b] = hn;
        }
    }
}

// 20 heads 20->32->32->1, grid (96 tb-groups, 20 heads), lane = b.
__global__ __launch_bounds__(64, 1) void heads_kernel(
    const float* __restrict__ hseq,
    const float* __restrict__ hw1, const float* __restrict__ hb1,
    const float* __restrict__ hw2, const float* __restrict__ hb2,
    const float* __restrict__ hw3, const float* __restrict__ hb3,
    float* __restrict__ out)
{
    const int t  = blockIdx.x >> 5, bg = blockIdx.x & 31;
    const int k  = blockIdx.y;
    const int b  = bg * 64 + threadIdx.x;

    float xv[20];
#pragma unroll
    for (int d = 0; d < 20; ++d)
        xv[d] = hseq[((size_t)t * 20 + d) * 2048 + b];

    float a1[32];
#pragma unroll
    for (int o = 0; o < 32; ++o) {
        float a = hb1[k * 32 + o];
        const float4* wr = (const float4*)(hw1 + ((size_t)k * 32 + o) * 20);
#pragma unroll
        for (int q = 0; q < 5; ++q) {
            const float4 w = wr[q];
            a = fmaf(w.x, xv[4 * q + 0], a); a = fmaf(w.y, xv[4 * q + 1], a);
            a = fmaf(w.z, xv[4 * q + 2], a); a = fmaf(w.w, xv[4 * q + 3], a);
        }
        a1[o] = fmaxf(a, 0.f);
    }
    float a2[32];
#pragma unroll
    for (int o = 0; o < 32; ++o) {
        float a = hb2[k * 32 + o];
        const float4* wr = (const float4*)(hw2 + ((size_t)k * 32 + o) * 32);
#pragma unroll
        for (int q = 0; q < 8; ++q) {
            const float4 w = wr[q];
            a = fmaf(w.x, a1[4 * q + 0], a); a = fmaf(w.y, a1[4 * q + 1], a);
            a = fmaf(w.z, a1[4 * q + 2], a); a = fmaf(w.w, a1[4 * q + 3], a);
        }
        a2[o] = fmaxf(a, 0.f);
    }
    float r = hb3[k];
    const float4* wr = (const float4*)(hw3 + (size_t)k * 32);
#pragma unroll
    for (int q = 0; q < 8; ++q) {
        const float4 w = wr[q];
        r = fmaf(w.x, a2[4 * q + 0], r); r = fmaf(w.y, a2[4 * q + 1], r);
        r = fmaf(w.z, a2[4 * q + 2], r); r = fmaf(w.w, a2[4 * q + 3], r);
    }
    out[((size_t)k * 3 + t) * 2048 + b] = r;
}

// ---------------------------------------------------------------------------
extern "C" void kernel_launch(void* const* d_in, const int* in_sizes, int n_in,
                              void* d_out, int out_size, void* d_ws, size_t ws_size,
                              hipStream_t stream)
{
    const float* img = (const float*)d_in[0];
    const float* ew0 = (const float*)d_in[1];  const float* eb0 = (const float*)d_in[2];
    const float* ew1 = (const float*)d_in[3];  const float* eb1 = (const float*)d_in[4];
    const float* ew2 = (const float*)d_in[5];  const float* eb2 = (const float*)d_in[6];
    const float* ew3 = (const float*)d_in[7];  const float* eb3 = (const float*)d_in[8];
    const float* ew4 = (const float*)d_in[9];  const float* eb4 = (const float*)d_in[10];
    const float* ew5 = (const float*)d_in[11]; const float* eb5 = (const float*)d_in[12];
    const float* mw1 = (const float*)d_in[13]; const float* mb1 = (const float*)d_in[14];
    const float* mw2 = (const float*)d_in[15]; const float* mb2 = (const float*)d_in[16];
    const float* mw3 = (const float*)d_in[17]; const float* mb3 = (const float*)d_in[18];
    const float* wih = (const float*)d_in[19]; const float* whh = (const float*)d_in[20];
    const float* bih = (const float*)d_in[21]; const float* bhh = (const float*)d_in[22];
    const float* hw1 = (const float*)d_in[23]; const float* hb1 = (const float*)d_in[24];
    const float* hw2 = (const float*)d_in[25]; const float* hb2 = (const float*)d_in[26];
    const float* hw3 = (const float*)d_in[27]; const float* hb3 = (const float*)d_in[28];

    // ws layout (floats), with buffer reuse:
    //   A: 25,165,824 f (a0 [3][4][32][32][2048]; later a2, then a4)
    //   B: 12,582,912 f (a1 [3][8][16][16][2048]; later a3; then xg+hseq)
    //   C:    786,432 f (feats [3][128][2048])
    float* A  = (float*)d_ws;
    float* B  = A + 25165824;
    float* C  = B + 12582912;
    float* XG = B;               // a3 dead after conv4: xg [3][80][2048]
    float* HS = B + 491520;      // hseq [3][20][2048]

    conv0_kernel<<<1536, 256, 0, stream>>>(img, ew0, eb0, A);
    conv1_kernel<<< 768, 256, 0, stream>>>(A, ew1, eb1, B);
    conv2_kernel<<< 768, 256, 0, stream>>>(B, ew2, eb2, A);
    conv3_kernel<<< 384, 256, 0, stream>>>(A, ew3, eb3, B);
    conv4_kernel<<< 384, 256, 0, stream>>>(B, ew4, eb4, A);
    conv5_kernel<<< 768, 256, 0, stream>>>(A, ew5, eb5, C);
    mlpxg_kernel<<<96, 64, 0, stream>>>(C, mw1, mb1, mw2, mb2, mw3, mb3,
                                        wih, bih, bhh, XG);
    lstm_kernel<<<32, 64, 0, stream>>>(XG, whh, HS);
    heads_kernel<<<dim3(96, 20), 64, 0, stream>>>(HS, hw1, hb1, hw2, hb2,
                                                  hw3, hb3, (float*)d_out);
}

// Round 4
// 1001.961 us; speedup vs baseline: 1.0807x; 1.0767x over previous
//
#include <hip/hip_runtime.h>
#include <math.h>

#define T_DIM 3
#define B_DIM 2048
#define NIMG  (T_DIM * B_DIM)   // 6144

// ===========================================================================
// Activations live in ws as [t][C][H][W][2048] fp32 (innermost = batch b).
// lane = image => coalesced loads on img-minor tensors, wave-uniform weights.
// ===========================================================================
__global__ __launch_bounds__(256) void conv0_kernel(
    const float* __restrict__ img, const float* __restrict__ w0,
    const float* __restrict__ b0, float* __restrict__ a0)
{
    __shared__ float sb[2][64 * 68];    // 34.8 KB: two (ci,ih) row-sets

    const int bid  = blockIdx.x;
    const int ohp  = bid & 15;          // oh-pair index (oh = 2*ohp + oh_sub)
    const int g    = (bid >> 4) & 31;   // image group of 64
    const int t    = bid >> 9;
    const int tid  = threadIdx.x;
    const int wv   = tid >> 6;          // wave 0..3
    const int lane = tid & 63;
    const int oh_sub = wv >> 1;
    const int half   = wv & 1;
    const int oh   = ohp * 2 + oh_sub;
    const int ow0  = half * 16;
    const int im   = g * 64 + lane;

    // staging decomposition: 16 threads per image row, 4 passes of 16 images
    const int jj16 = tid >> 4;          // 0..15
    const int f4   = tid & 15;          // float4 chunk within 64-float row
    const int ih0  = 4 * ohp - 1;       // first ih of the 6-row window

    float acc[4][16];
#pragma unroll
    for (int j = 0; j < 4; j++) {
        const float bv = b0[t * 4 + j];
#pragma unroll
        for (int k = 0; k < 16; k++) acc[j][k] = bv;
    }
    const float* wt = w0 + t * 192;

    // stage (ci, ih) row-set into dst: dst[j*68 + iw] = row_j[iw]
    auto stage = [&](int ci, int ih, float* dst) {
        if ((unsigned)ih < 64u) {
#pragma unroll
            for (int p = 0; p < 4; ++p) {
                const int j = p * 16 + jj16;
                const float4 v = *(const float4*)(img +
                    ((size_t)((t * 2048 + g * 64 + j) * 3 + ci) << 12) +
                    (ih << 6) + (f4 << 2));
                *(float4*)&dst[j * 68 + (f4 << 2)] = v;
            }
        }
    };

    // consume one staged row: wave uses it iff its kh = r - 2*oh_sub in [0,4)
    auto consume = [&](int ci, int r, int ih, const float* src) {
        const int kh = r - 2 * oh_sub;
        if (kh < 0 || kh > 3 || (unsigned)ih >= 64u) return;
        const float* lrow = src + lane * 68;
        float tap[34];                  // tap[r] = input at iw = 2*ow0-1+r
        if (half == 0) {
            tap[0] = 0.f;               // iw = -1 (padding)
#pragma unroll
            for (int c = 0; c < 8; ++c) {
                const float4 v = *(const float4*)(lrow + 4 * c);
                tap[1 + 4 * c] = v.x; tap[2 + 4 * c] = v.y;
                tap[3 + 4 * c] = v.z; tap[4 + 4 * c] = v.w;
            }
            tap[33] = lrow[32];
        } else {
            tap[0] = lrow[31];
#pragma unroll
            for (int c = 0; c < 8; ++c) {
                const float4 v = *(const float4*)(lrow + 32 + 4 * c);
                tap[1 + 4 * c] = v.x; tap[2 + 4 * c] = v.y;
                tap[3 + 4 * c] = v.z; tap[4 + 4 * c] = v.w;
            }
            tap[33] = 0.f;              // iw = 64 (padding)
        }
        float w_[4][4];
#pragma unroll
        for (int j = 0; j < 4; j++)
#pragma unroll
            for (int kw = 0; kw < 4; kw++)
                w_[j][kw] = wt[((j * 3 + ci) * 4 + kh) * 4 + kw]; // uniform
#pragma unroll
        for (int jj = 0; jj < 16; jj++)
#pragma unroll
            for (int kw = 0; kw < 4; kw++) {
                const float x = tap[2 * jj + kw];
#pragma unroll
                for (int j = 0; j < 4; j++)
                    acc[j][jj] = fmaf(x, w_[j][kw], acc[j][jj]);
            }
    };

    // software pipeline over the 18 (ci, r) stages, double-buffered
    stage(0, ih0, sb[0]);
    __syncthreads();
    int s = 0;
#pragma unroll
    for (int ci = 0; ci < 3; ++ci)
#pragma unroll
        for (int r = 0; r < 6; ++r) {
            if (s < 17) {
                const int rn = (r == 5) ? 0 : r + 1;
                const int cn = (r == 5) ? ci + 1 : ci;
                stage(cn, ih0 + rn, sb[(s + 1) & 1]);
            }
            consume(ci, r, ih0 + r, sb[s & 1]);
            __syncthreads();
            ++s;
        }

    const size_t ob0 = ((size_t)(t * 4096 + oh * 32 + ow0)) * 2048 + im;
#pragma unroll
    for (int j = 0; j < 4; j++)
#pragma unroll
        for (int k = 0; k < 16; k++)
            a0[ob0 + ((size_t)j * 1024 + k) * 2048] = fmaxf(acc[j][k], 0.f);
}

// ---------------------------------------------------------------------------
// Generic mid conv (img-minor in AND out). Wave = (t, img-grp, co-grp, oh),
// full output row in registers. Border taps are compile-time zeros.
// ---------------------------------------------------------------------------
template<int CIN, int COUT, int IH, int OH, int CB>
__device__ __forceinline__ void convmid(
    const float* __restrict__ in, const float* __restrict__ gw,
    const float* __restrict__ gb, float* __restrict__ out,
    int t, int cg, int oh, int im)
{
    const int co0 = cg * CB;
    float acc[CB][OH];
#pragma unroll
    for (int j = 0; j < CB; j++) {
        const float bv = gb[t * COUT + co0 + j];
#pragma unroll
        for (int k = 0; k < OH; k++) acc[j][k] = bv;
    }
    const float* wt = gw + ((size_t)t * COUT + co0) * CIN * 16;
    const size_t inb = ((size_t)t * CIN) * (IH * IH) * 2048 + im;

#pragma unroll 4
    for (int ci = 0; ci < CIN; ci++) {
#pragma unroll
        for (int kh = 0; kh < 4; kh++) {
            const int ih = 2 * oh - 1 + kh;
            if ((unsigned)ih >= (unsigned)IH) continue;  // wave-uniform
            const float* rp = in + inb + (size_t)(ci * IH + ih) * IH * 2048;
            float tap[IH + 2];
            tap[0] = 0.f; tap[IH + 1] = 0.f;
#pragma unroll
            for (int iw = 0; iw < IH; iw++) tap[iw + 1] = rp[(size_t)iw * 2048];
            float w_[CB][4];
#pragma unroll
            for (int j = 0; j < CB; j++)
#pragma unroll
                for (int kw = 0; kw < 4; kw++)
                    w_[j][kw] = wt[((size_t)j * CIN + ci) * 16 + kh * 4 + kw];
#pragma unroll
            for (int ow = 0; ow < OH; ow++)
#pragma unroll
                for (int kw = 0; kw < 4; kw++) {
                    const float x = tap[2 * ow + kw];
#pragma unroll
                    for (int j = 0; j < CB; j++)
                        acc[j][ow] = fmaf(x, w_[j][kw], acc[j][ow]);
                }
        }
    }
    const size_t ob = ((size_t)(t * COUT + co0) * OH * OH + (size_t)oh * OH) * 2048 + im;
#pragma unroll
    for (int j = 0; j < CB; j++)
#pragma unroll
        for (int k = 0; k < OH; k++)
            out[ob + ((size_t)j * OH * OH + k) * 2048] = fmaxf(acc[j][k], 0.f);
}

__global__ __launch_bounds__(256) void conv1_kernel(
    const float* __restrict__ a0, const float* __restrict__ w,
    const float* __restrict__ b, float* __restrict__ a1)
{
    const int wid = blockIdx.x * 4 + (threadIdx.x >> 6);
    const int lane = threadIdx.x & 63;
    const int oh = wid & 15, cg = (wid >> 4) & 1, g = (wid >> 5) & 31, t = wid >> 10;
    convmid<4, 8, 32, 16, 4>(a0, w, b, a1, t, cg, oh, g * 64 + lane);
}

__global__ __launch_bounds__(256) void conv2_kernel(
    const float* __restrict__ a1, const float* __restrict__ w,
    const float* __restrict__ b, float* __restrict__ a2)
{
    const int wid = blockIdx.x * 4 + (threadIdx.x >> 6);
    const int lane = threadIdx.x & 63;
    const int oh = wid & 7, cg = (wid >> 3) & 3, g = (wid >> 5) & 31, t = wid >> 10;
    convmid<8, 16, 16, 8, 4>(a1, w, b, a2, t, cg, oh, g * 64 + lane);
}

__global__ __launch_bounds__(256) void conv3_kernel(
    const float* __restrict__ a2, const float* __restrict__ w,
    const float* __restrict__ b, float* __restrict__ a3)
{
    const int wid = blockIdx.x * 4 + (threadIdx.x >> 6);
    const int lane = threadIdx.x & 63;
    const int oh = wid & 3, cg = (wid >> 2) & 3, g = (wid >> 4) & 31, t = wid >> 9;
    convmid<16, 32, 8, 4, 8>(a2, w, b, a3, t, cg, oh, g * 64 + lane);
}

// ---------------------------------------------------------------------------
// Layer 4: [32][4][4] -> [64][2][2]. CB=4 (16 co-groups) => 384 blocks.
// ---------------------------------------------------------------------------
__global__ __launch_bounds__(256) void conv4_kernel(
    const float* __restrict__ a3, const float* __restrict__ w4,
    const float* __restrict__ b4, float* __restrict__ a4)
{
    const int wid = blockIdx.x * 4 + (threadIdx.x >> 6);
    const int lane = threadIdx.x & 63;
    const int cg = wid & 15, g = (wid >> 4) & 31, t = wid >> 9;
    const int im = g * 64 + lane;
    const int co0 = cg * 4;

    float acc[4][4];
#pragma unroll
    for (int j = 0; j < 4; j++) {
        const float bv = b4[t * 64 + co0 + j];
#pragma unroll
        for (int p = 0; p < 4; p++) acc[j][p] = bv;
    }
    const float* wt = w4 + ((size_t)t * 64 + co0) * 32 * 16;
    const size_t inb = ((size_t)t * 32) * 16 * 2048 + im;

    for (int ci = 0; ci < 32; ci++) {
        float tin[16];
#pragma unroll
        for (int p = 0; p < 16; p++)
            tin[p] = a3[inb + ((size_t)ci * 16 + p) * 2048];
#pragma unroll
        for (int kh = 0; kh < 4; kh++)
#pragma unroll
            for (int oh = 0; oh < 2; oh++) {
                const int ih = 2 * oh - 1 + kh;
                if (ih < 0 || ih > 3) continue;          // compile-time
#pragma unroll
                for (int ow = 0; ow < 2; ow++)
#pragma unroll
                    for (int kw = 0; kw < 4; kw++) {
                        const int iw = 2 * ow - 1 + kw;
                        if (iw < 0 || iw > 3) continue;  // compile-time
                        const float x = tin[ih * 4 + iw];
#pragma unroll
                        for (int j = 0; j < 4; j++)
                            acc[j][oh * 2 + ow] = fmaf(
                                x, wt[((size_t)j * 32 + ci) * 16 + kh * 4 + kw],
                                acc[j][oh * 2 + ow]);
                    }
            }
    }
#pragma unroll
    for (int j = 0; j < 4; j++)
#pragma unroll
        for (int p = 0; p < 4; p++)
            a4[(((size_t)t * 64 + co0 + j) * 4 + p) * 2048 + im] =
                fmaxf(acc[j][p], 0.f);
}

// ---------------------------------------------------------------------------
// Layer 5: [64][2][2] -> [128]. Only taps (1,1),(1,2),(2,1),(2,2) valid.
// ---------------------------------------------------------------------------
__global__ __launch_bounds__(256) void conv5_kernel(
    const float* __restrict__ a4, const float* __restrict__ w5,
    const float* __restrict__ b5, float* __restrict__ feats)
{
    const int wid = blockIdx.x * 4 + (threadIdx.x >> 6);
    const int lane = threadIdx.x & 63;
    const int cg = wid & 31, g = (wid >> 5) & 31, t = wid >> 10;
    const int im = g * 64 + lane;
    const int co0 = cg * 4;

    float acc[4];
#pragma unroll
    for (int j = 0; j < 4; j++) acc[j] = b5[t * 128 + co0 + j];
    const float* wt = w5 + ((size_t)t * 128 + co0) * 64 * 16;
    const size_t inb = ((size_t)t * 64) * 4 * 2048 + im;

#pragma unroll 4
    for (int ci = 0; ci < 64; ci++) {
        const float x0 = a4[inb + ((size_t)ci * 4 + 0) * 2048];
        const float x1 = a4[inb + ((size_t)ci * 4 + 1) * 2048];
        const float x2 = a4[inb + ((size_t)ci * 4 + 2) * 2048];
        const float x3 = a4[inb + ((size_t)ci * 4 + 3) * 2048];
#pragma unroll
        for (int j = 0; j < 4; j++) {
            const size_t wb = ((size_t)j * 64 + ci) * 16;
            acc[j] = fmaf(x0, wt[wb + 5],  acc[j]);
            acc[j] = fmaf(x1, wt[wb + 6],  acc[j]);
            acc[j] = fmaf(x2, wt[wb + 9],  acc[j]);
            acc[j] = fmaf(x3, wt[wb + 10], acc[j]);
        }
    }
#pragma unroll
    for (int j = 0; j < 4; j++)
        feats[((size_t)t * 128 + co0 + j) * 2048 + im] = fmaxf(acc[j], 0.f);
}

// ===========================================================================
// Tail. Round-1/2 lesson: the monolithic per-thread MLP (260 live floats,
// 4-deep unrolled nests) was demoted to scratch by the middle-end (VGPR=84
// both with and without launch_bounds => alloca, not RA spill). Rebuilt so
// spill is impossible by construction:
//   - no ReLU after mlp_w3  =>  fold  WX = w_ih @ mw3  [80x32],
//     BX = w_ih @ mb3 + b_ih + b_hh  [80]  (fusew_kernel, ~165 KFLOP).
//   - per-thread chain 128->32->32->(80 streamed): peak live ~50 floats.
//   - arrays indexed ONLY by small fully-unrolled loops; streaming loops
//     (d4, i) index no arrays (accumulators = loop-carried phis).
// ===========================================================================

__global__ __launch_bounds__(256) void fusew_kernel(
    const float* __restrict__ wih, const float* __restrict__ mw3,
    const float* __restrict__ mb3, const float* __restrict__ bih,
    const float* __restrict__ bhh, float* __restrict__ WX,
    float* __restrict__ BX)
{
    const int idx = blockIdx.x * 256 + threadIdx.x;
    if (idx < 2560) {                        // WX[i][d] = sum_o wih[i][o] mw3[o][d]
        const int i = idx >> 5, d = idx & 31;
        float a = 0.f;
        for (int o = 0; o < 64; ++o)
            a = fmaf(wih[i * 64 + o], mw3[o * 32 + d], a);
        WX[idx] = a;
    } else if (idx < 2640) {                 // BX[i] = bih+bhh + wih[i]·mb3
        const int i = idx - 2560;
        float a = bih[i] + bhh[i];
        for (int o = 0; o < 64; ++o)
            a = fmaf(wih[i * 64 + o], mb3[o], a);
        BX[i] = a;
    }
}

// feats -> h1(relu) -> h2(relu) -> xg[80] (via fused WX/BX), lane = b.
__global__ __launch_bounds__(64, 1) void mlpxg_kernel(
    const float* __restrict__ feats,
    const float* __restrict__ mw1, const float* __restrict__ mb1,
    const float* __restrict__ mw2, const float* __restrict__ mb2,
    const float* __restrict__ WX,  const float* __restrict__ BX,
    float* __restrict__ xg)
{
    const int t  = blockIdx.x >> 5, bg = blockIdx.x & 31;
    const int b  = bg * 64 + threadIdx.x;

    float h1[32];
#pragma unroll
    for (int o = 0; o < 32; ++o) h1[o] = mb1[o];

    const float* fb = feats + (size_t)t * 128 * 2048 + b;
    for (int d4 = 0; d4 < 32; ++d4) {        // streaming: indexes no array
        const float x0 = fb[(size_t)(4 * d4 + 0) * 2048];
        const float x1 = fb[(size_t)(4 * d4 + 1) * 2048];
        const float x2 = fb[(size_t)(4 * d4 + 2) * 2048];
        const float x3 = fb[(size_t)(4 * d4 + 3) * 2048];
#pragma unroll
        for (int o = 0; o < 32; ++o) {
            const float4 w = *(const float4*)(mw1 + o * 128 + 4 * d4); // uniform
            h1[o] = fmaf(w.w, x3, fmaf(w.z, x2, fmaf(w.y, x1,
                    fmaf(w.x, x0, h1[o]))));
        }
    }
#pragma unroll
    for (int o = 0; o < 32; ++o) h1[o] = fmaxf(h1[o], 0.f);

    float h2[32];
#pragma unroll
    for (int o = 0; o < 32; ++o) {
        float a = mb2[o];
#pragma unroll
        for (int d = 0; d < 32; ++d)
            a = fmaf(mw2[o * 32 + d], h1[d], a);         // uniform weight
        h2[o] = fmaxf(a, 0.f);
    }

    float* xb = xg + (size_t)t * 80 * 2048 + b;
#pragma unroll 4
    for (int i = 0; i < 80; ++i) {           // streaming: indexes no array
        float a = BX[i];
#pragma unroll
        for (int d = 0; d < 32; ++d)
            a = fmaf(WX[i * 32 + d], h2[d], a);          // uniform weight
        xb[(size_t)i * 2048] = a;
    }
}

// LSTM recurrence (x-gemm precomputed into xg). Per gate-row j: 4 direct
// dots against h_old; state = h[20]+c[20]+hn[20] (~65 live floats).
__global__ __launch_bounds__(64, 1) void lstm_kernel(
    const float* __restrict__ xg, const float* __restrict__ whh,
    float* __restrict__ hseq)
{
    const int b = blockIdx.x * 64 + threadIdx.x;
    float h[20], c[20];
#pragma unroll
    for (int j = 0; j < 20; ++j) { h[j] = 0.f; c[j] = 0.f; }

    for (int t = 0; t < 3; ++t) {
        const float* xb = xg + (size_t)t * 80 * 2048 + b;
        float hn[20];
#pragma unroll
        for (int j = 0; j < 20; ++j) {       // torch gate order i,f,g,o
            float ai = xb[(size_t)(j +  0) * 2048];
            float af = xb[(size_t)(j + 20) * 2048];
            float ag = xb[(size_t)(j + 40) * 2048];
            float ao = xb[(size_t)(j + 60) * 2048];
#pragma unroll
            for (int d = 0; d < 20; ++d) {
                const float hv = h[d];
                ai = fmaf(whh[(j +  0) * 20 + d], hv, ai);
                af = fmaf(whh[(j + 20) * 20 + d], hv, af);
                ag = fmaf(whh[(j + 40) * 20 + d], hv, ag);
                ao = fmaf(whh[(j + 60) * 20 + d], hv, ao);
            }
            const float ig = 1.f / (1.f + expf(-ai));
            const float fg = 1.f / (1.f + expf(-af));
            const float gt = tanhf(ag);
            const float og = 1.f / (1.f + expf(-ao));
            const float cn = fg * c[j] + ig * gt;
            c[j]  = cn;
            hn[j] = og * tanhf(cn);
            hseq[((size_t)t * 20 + j) * 2048 + b] = hn[j];
        }
#pragma unroll
        for (int j = 0; j < 20; ++j) h[j] = hn[j];
    }
}

// 20 heads 20->32->32->1, grid (96 tb-groups, 20 heads), lane = b.
__global__ __launch_bounds__(64, 1) void heads_kernel(
    const float* __restrict__ hseq,
    const float* __restrict__ hw1, const float* __restrict__ hb1,
    const float* __restrict__ hw2, const float* __restrict__ hb2,
    const float* __restrict__ hw3, const float* __restrict__ hb3,
    float* __restrict__ out)
{
    const int t  = blockIdx.x >> 5, bg = blockIdx.x & 31;
    const int k  = blockIdx.y;
    const int b  = bg * 64 + threadIdx.x;

    float xv[20];
#pragma unroll
    for (int d = 0; d < 20; ++d)
        xv[d] = hseq[((size_t)t * 20 + d) * 2048 + b];

    float a1[32];
#pragma unroll
    for (int o = 0; o < 32; ++o) {
        float a = hb1[k * 32 + o];
#pragma unroll
        for (int d = 0; d < 20; ++d)
            a = fmaf(hw1[((size_t)k * 32 + o) * 20 + d], xv[d], a);
        a1[o] = fmaxf(a, 0.f);
    }
    float a2[32];
#pragma unroll
    for (int o = 0; o < 32; ++o) {
        float a = hb2[k * 32 + o];
#pragma unroll
        for (int d = 0; d < 32; ++d)
            a = fmaf(hw2[((size_t)k * 32 + o) * 32 + d], a1[d], a);
        a2[o] = fmaxf(a, 0.f);
    }
    float r = hb3[k];
#pragma unroll
    for (int d = 0; d < 32; ++d)
        r = fmaf(hw3[(size_t)k * 32 + d], a2[d], r);
    out[((size_t)k * 3 + t) * 2048 + b] = r;
}

// ---------------------------------------------------------------------------
extern "C" void kernel_launch(void* const* d_in, const int* in_sizes, int n_in,
                              void* d_out, int out_size, void* d_ws, size_t ws_size,
                              hipStream_t stream)
{
    const float* img = (const float*)d_in[0];
    const float* ew0 = (const float*)d_in[1];  const float* eb0 = (const float*)d_in[2];
    const float* ew1 = (const float*)d_in[3];  const float* eb1 = (const float*)d_in[4];
    const float* ew2 = (const float*)d_in[5];  const float* eb2 = (const float*)d_in[6];
    const float* ew3 = (const float*)d_in[7];  const float* eb3 = (const float*)d_in[8];
    const float* ew4 = (const float*)d_in[9];  const float* eb4 = (const float*)d_in[10];
    const float* ew5 = (const float*)d_in[11]; const float* eb5 = (const float*)d_in[12];
    const float* mw1 = (const float*)d_in[13]; const float* mb1 = (const float*)d_in[14];
    const float* mw2 = (const float*)d_in[15]; const float* mb2 = (const float*)d_in[16];
    const float* mw3 = (const float*)d_in[17]; const float* mb3 = (const float*)d_in[18];
    const float* wih = (const float*)d_in[19]; const float* whh = (const float*)d_in[20];
    const float* bih = (const float*)d_in[21]; const float* bhh = (const float*)d_in[22];
    const float* hw1 = (const float*)d_in[23]; const float* hb1 = (const float*)d_in[24];
    const float* hw2 = (const float*)d_in[25]; const float* hb2 = (const float*)d_in[26];
    const float* hw3 = (const float*)d_in[27]; const float* hb3 = (const float*)d_in[28];

    // ws layout (floats), with buffer reuse:
    //   A: 25,165,824 f (a0 [3][4][32][32][2048]; later a2, then a4)
    //   B: 12,582,912 f (a1 [3][8][16][16][2048]; later a3; then xg+hseq)
    //   C:    786,432 f (feats [3][128][2048])
    //   D:      2,640 f (WX [80][32], BX [80])
    float* A  = (float*)d_ws;
    float* B  = A + 25165824;
    float* C  = B + 12582912;
    float* D  = C + 786432;
    float* XG = B;               // a3 dead after conv4: xg [3][80][2048]
    float* HS = B + 491520;      // hseq [3][20][2048]
    float* WX = D;
    float* BX = D + 2560;

    fusew_kernel<<<11, 256, 0, stream>>>(wih, mw3, mb3, bih, bhh, WX, BX);
    conv0_kernel<<<1536, 256, 0, stream>>>(img, ew0, eb0, A);
    conv1_kernel<<< 768, 256, 0, stream>>>(A, ew1, eb1, B);
    conv2_kernel<<< 768, 256, 0, stream>>>(B, ew2, eb2, A);
    conv3_kernel<<< 384, 256, 0, stream>>>(A, ew3, eb3, B);
    conv4_kernel<<< 384, 256, 0, stream>>>(B, ew4, eb4, A);
    conv5_kernel<<< 768, 256, 0, stream>>>(A, ew5, eb5, C);
    mlpxg_kernel<<<96, 64, 0, stream>>>(C, mw1, mb1, mw2, mb2, WX, BX, XG);
    lstm_kernel<<<32, 64, 0, stream>>>(XG, whh, HS);
    heads_kernel<<<dim3(96, 20), 64, 0, stream>>>(HS, hw1, hb1, hw2, hb2,
                                                  hw3, hb3, (float*)d_out);
}